// Round 1
// baseline (108.336 us; speedup 1.0000x reference)
//
#include <hip/hip_runtime.h>

namespace {

constexpr int NN  = 256;             // FFT length along each axis
constexpr int BMN = 256 * 256 * 256; // elements per component

struct cpx { float re, im; };

__device__ __forceinline__ cpx cadd(cpx a, cpx b){ return cpx{a.re + b.re, a.im + b.im}; }
__device__ __forceinline__ cpx csub(cpx a, cpx b){ return cpx{a.re - b.re, a.im - b.im}; }
__device__ __forceinline__ cpx cmul(cpx a, cpx b){ return cpx{a.re*b.re - a.im*b.im, a.re*b.im + a.im*b.re}; }
__device__ __forceinline__ cpx cmuli(cpx a){ return cpx{-a.im, a.re}; }  // multiply by +i (inverse transform)

// radix-4 inverse butterfly: y[k] = sum_n x[n] * e^{+2pi i nk/4}
__device__ __forceinline__ void r4(cpx a, cpx b, cpx c, cpx d,
                                   cpx& y0, cpx& y1, cpx& y2, cpx& y3) {
  cpx apc = cadd(a, c), amc = csub(a, c);
  cpx bpd = cadd(b, d), bmd = csub(b, d);
  cpx ib  = cmuli(bmd);
  y0 = cadd(apc, bpd);
  y1 = cadd(amc, ib);
  y2 = csub(apc, bpd);
  y3 = csub(amc, ib);
}

// 16-point inverse DFT (unnormalized), natural order in/out, fully in registers.
// Decomposition: n = n1 + 4*n2, k = k2 + 4*k1.
__device__ __forceinline__ void ifft16(cpx x[16]) {
  // W16^m = e^{+2pi i m/16}, m = 0..9
  constexpr float WC[10] = { 1.f,  0.9238795325112867f,  0.7071067811865476f,  0.3826834323650898f, 0.f,
                            -0.3826834323650898f, -0.7071067811865476f, -0.9238795325112867f, -1.f,
                            -0.9238795325112867f };
  constexpr float WS[10] = { 0.f,  0.3826834323650898f,  0.7071067811865476f,  0.9238795325112867f, 1.f,
                             0.9238795325112867f,  0.7071067811865476f,  0.3826834323650898f,  0.f,
                            -0.3826834323650898f };
  cpx B[4][4];
#pragma unroll
  for (int n1 = 0; n1 < 4; ++n1)
    r4(x[n1], x[n1 + 4], x[n1 + 8], x[n1 + 12],
       B[n1][0], B[n1][1], B[n1][2], B[n1][3]);
#pragma unroll
  for (int n1 = 1; n1 < 4; ++n1)
#pragma unroll
    for (int k2 = 1; k2 < 4; ++k2)
      B[n1][k2] = cmul(B[n1][k2], cpx{WC[n1 * k2], WS[n1 * k2]});
#pragma unroll
  for (int k2 = 0; k2 < 4; ++k2)
    r4(B[0][k2], B[1][k2], B[2][k2], B[3][k2],
       x[k2], x[k2 + 4], x[k2 + 8], x[k2 + 12]);
}

// multiply a[k1] by W256^{t*k1} = e^{+2pi i t k1/256}
__device__ __forceinline__ void twiddle256(cpx a[16], int t) {
  const float base = 0.024543692606170259f * (float)t;  // 2*pi/256 * t
#pragma unroll
  for (int k1 = 1; k1 < 16; ++k1) {
    float s, c;
    __sincosf(base * (float)k1, &s, &c);
    a[k1] = cmul(a[k1], cpx{c, s});
  }
}

// ------- kernel 1: IFFT along last axis (contiguous), with shift folded in -------
// line = b*256 + m. 16 threads per line (t = n2), 16 lines per block.
__global__ __launch_bounds__(256)
void k_ifft_rows(const float* __restrict__ xr, const float* __restrict__ xi,
                 float* __restrict__ yr, float* __restrict__ yi) {
  __shared__ float lr[16 * 273];
  __shared__ float li[16 * 273];
  const int tid  = threadIdx.x;
  const int t    = tid & 15;
  const int ll   = tid >> 4;
  const int line = blockIdx.x * 16 + ll;
  const float* pr = xr + line * NN;
  const float* pi = xi + line * NN;

  cpx a[16];
#pragma unroll
  for (int j = 0; j < 16; ++j) {
    const int idx = (((j << 4) | t) ^ 128);   // ifftshift on load
    a[j] = cpx{ pr[idx], pi[idx] };
  }
  ifft16(a);            // a[k1] = A[k1][n2=t]
  twiddle256(a, t);     // * W256^{t*k1}

  float* Lr = lr + ll * 273;
  float* Li = li + ll * 273;
#pragma unroll
  for (int k1 = 0; k1 < 16; ++k1) { Lr[k1 * 17 + t] = a[k1].re; Li[k1 * 17 + t] = a[k1].im; }
  __syncthreads();
#pragma unroll
  for (int n2 = 0; n2 < 16; ++n2) { a[n2].re = Lr[t * 17 + n2]; a[n2].im = Li[t * 17 + n2]; }

  ifft16(a);            // a[k2] = X[t + 16*k2]
  float* qr = yr + line * NN;
  float* qi = yi + line * NN;
#pragma unroll
  for (int k = 0; k < 16; ++k) {
    const int idx = (((k << 4) | t) ^ 128);   // fftshift on store
    qr[idx] = a[k].re;
    qi[idx] = a[k].im;
  }
}

// ------- kernel 2: IFFT along axis -2 (stride 256), in-place on d_out -------
// block: image b = blockIdx>>4, 16 columns starting at c0; c fastest for coalescing.
__global__ __launch_bounds__(256)
void k_ifft_cols(float* __restrict__ yr, float* __restrict__ yi) {
  __shared__ float lr[16 * 273];
  __shared__ float li[16 * 273];
  const int tid = threadIdx.x;
  const int c   = tid & 15;
  const int t   = tid >> 4;
  const int b   = blockIdx.x >> 4;
  const int c0  = (blockIdx.x & 15) << 4;
  const int base = b * 65536 + c0 + c;

  cpx a[16];
#pragma unroll
  for (int j = 0; j < 16; ++j) {
    const int m = (((j << 4) | t) ^ 128);     // ifftshift on load
    a[j] = cpx{ yr[base + m * NN], yi[base + m * NN] };
  }
  ifft16(a);
  twiddle256(a, t);

  float* Lr = lr + c * 273;
  float* Li = li + c * 273;
#pragma unroll
  for (int k1 = 0; k1 < 16; ++k1) { Lr[k1 * 17 + t] = a[k1].re; Li[k1 * 17 + t] = a[k1].im; }
  __syncthreads();
#pragma unroll
  for (int n2 = 0; n2 < 16; ++n2) { a[n2].re = Lr[t * 17 + n2]; a[n2].im = Li[t * 17 + n2]; }

  ifft16(a);
  constexpr float sc = 1.0f / 65536.0f;       // ifft2 normalization
#pragma unroll
  for (int k = 0; k < 16; ++k) {
    const int m = (((k << 4) | t) ^ 128);     // fftshift on store
    yr[base + m * NN] = a[k].re * sc;
    yi[base + m * NN] = a[k].im * sc;
  }
}

} // namespace

extern "C" void kernel_launch(void* const* d_in, const int* in_sizes, int n_in,
                              void* d_out, int out_size, void* d_ws, size_t ws_size,
                              hipStream_t stream) {
  const float* xr = (const float*)d_in[0];
  const float* xi = (const float*)d_in[1];
  float* yr = (float*)d_out;        // real part of output
  float* yi = yr + BMN;             // imag part of output

  // 65536 lines / 16 per block
  k_ifft_rows<<<4096, 256, 0, stream>>>(xr, xi, yr, yi);
  // 256 images * 16 column-tiles
  k_ifft_cols<<<4096, 256, 0, stream>>>(yr, yi);
}